// Round 1
// baseline (7687.225 us; speedup 1.0000x reference)
//
#include <hip/hip_runtime.h>
#include <cstdint>
#include <cstddef>

#define T_STEPS 512
#define HID 40
#define GATES 120

// One wave (64 lanes) per batch element, persistent over all T timesteps.
// Lane l owns gate rows l and l+64 (120 gates total: r=0..39, z=40..79, n=80..119).
// Gate weights (wih,whh rows) live in VGPRs; h and x are broadcast from LDS.
// Optional fused position-wise MLP (leaky_relu(x@w1^T+b1)@w2^T+b2) on the input.
template<int DIN, bool FUSE_MLP, bool WRITE_ALL>
__global__ __launch_bounds__(256, 2) void gru_fused(
    const float* __restrict__ in,    // [CB, T, DIN]
    float* __restrict__ out,         // [CB, T, HID] or [CB, HID] if !WRITE_ALL
    const float* __restrict__ wih,   // [120, DIN]
    const float* __restrict__ whh,   // [120, 40]
    const float* __restrict__ bih,   // [120]
    const float* __restrict__ bhh,   // [120]
    const float* __restrict__ mw1,   // [40,40] (fused MLP) or null
    const float* __restrict__ mb1,   // [40]
    const float* __restrict__ mw2,   // [40,40]
    const float* __restrict__ mb2)   // [40]
{
    __shared__ float s_in[4][HID];       // raw input (pre-MLP), fused path only
    __shared__ float s_x[4][HID];        // GRU input for this step
    __shared__ float s_a[4][HID];        // MLP hidden
    __shared__ float s_h[4][HID];        // recurrent state
    __shared__ float s_sum[4][GATES];    // sx+sh per gate
    __shared__ float s_shn[4][HID];      // sh for n-gates
    __shared__ float s_w1[HID][HID + 1]; // padded to dodge bank conflicts
    __shared__ float s_w2[HID][HID + 1];
    __shared__ float s_b1[HID];
    __shared__ float s_b2[HID];

    const int tid  = threadIdx.x;
    const int w    = tid >> 6;   // wave index in block = element slot
    const int lane = tid & 63;
    const int e    = blockIdx.x * 4 + w;

    if constexpr (FUSE_MLP) {
        for (int i = tid; i < HID * HID; i += 256) {
            s_w1[i / HID][i % HID] = mw1[i];
            s_w2[i / HID][i % HID] = mw2[i];
        }
        if (tid < HID) { s_b1[tid] = mb1[tid]; s_b2[tid] = mb2[tid]; }
    }

    // per-lane gate rows
    const int  g0   = lane;                  // 0..63
    const bool has1 = lane < (GATES - 64);   // lanes 0..55 own a 2nd gate
    const int  g1   = has1 ? (64 + lane) : 0;

    float wi0[DIN], wi1[DIN], wh0[HID], wh1[HID];
    {
        const float4* wv = reinterpret_cast<const float4*>(wih);
        #pragma unroll
        for (int k = 0; k < DIN / 4; ++k) {
            reinterpret_cast<float4*>(wi0)[k] = wv[g0 * (DIN / 4) + k];
            reinterpret_cast<float4*>(wi1)[k] = wv[g1 * (DIN / 4) + k];
        }
        const float4* hv = reinterpret_cast<const float4*>(whh);
        #pragma unroll
        for (int k = 0; k < HID / 4; ++k) {
            reinterpret_cast<float4*>(wh0)[k] = hv[g0 * (HID / 4) + k];
            reinterpret_cast<float4*>(wh1)[k] = hv[g1 * (HID / 4) + k];
        }
    }
    const float bi0 = bih[g0], bh0 = bhh[g0];
    const float bi1 = has1 ? bih[g1] : 0.f;
    const float bh1 = has1 ? bhh[g1] : 0.f;

    if (lane < HID) s_h[w][lane] = 0.f;
    __syncthreads();

    const float* inbase = in + (size_t)e * T_STEPS * DIN;

    for (int t = 0; t < T_STEPS; ++t) {
        // ---- stage this step's raw input (each wave stages its own element) ----
        if constexpr (FUSE_MLP) {
            if (lane < DIN) s_in[w][lane] = inbase[t * DIN + lane];
        } else {
            if (lane < DIN) s_x[w][lane] = inbase[t * DIN + lane];
        }
        __syncthreads();   // SYNC_A: input staged; prev step's h update visible

        if constexpr (FUSE_MLP) {
            if (lane < HID) {
                float acc = s_b1[lane];
                #pragma unroll
                for (int d = 0; d < HID; ++d) acc += s_w1[lane][d] * s_in[w][d];
                s_a[w][lane] = acc > 0.f ? acc : 0.01f * acc;
            }
            __syncthreads();
            if (lane < HID) {
                float acc = s_b2[lane];
                #pragma unroll
                for (int d = 0; d < HID; ++d) acc += s_w2[lane][d] * s_a[w][d];
                s_x[w][lane] = acc;
            }
            __syncthreads();
        }

        // ---- gate dot products (uniform-broadcast LDS reads, register weights) ----
        float sx0 = bi0, sx1 = bi1, sh0 = bh0, sh1 = bh1;
        #pragma unroll
        for (int k = 0; k < DIN / 4; ++k) {
            const float4 v = reinterpret_cast<float4*>(s_x[w])[k];
            sx0 += wi0[4*k+0]*v.x + wi0[4*k+1]*v.y + wi0[4*k+2]*v.z + wi0[4*k+3]*v.w;
            sx1 += wi1[4*k+0]*v.x + wi1[4*k+1]*v.y + wi1[4*k+2]*v.z + wi1[4*k+3]*v.w;
        }
        #pragma unroll
        for (int k = 0; k < HID / 4; ++k) {
            const float4 v = reinterpret_cast<float4*>(s_h[w])[k];
            sh0 += wh0[4*k+0]*v.x + wh0[4*k+1]*v.y + wh0[4*k+2]*v.z + wh0[4*k+3]*v.w;
            sh1 += wh1[4*k+0]*v.x + wh1[4*k+1]*v.y + wh1[4*k+2]*v.z + wh1[4*k+3]*v.w;
        }
        s_sum[w][g0] = sx0 + sh0;
        if (has1) {
            s_sum[w][g1] = sx1 + sh1;
            if (g1 >= 80) s_shn[w][g1 - 80] = sh1;   // n-gate: keep sh separately
        }
        __syncthreads();   // SYNC_B: all gate sums written

        // ---- per-unit activation + state update (lanes 0..39) ----
        if (lane < HID) {
            const float r  = 1.f / (1.f + __expf(-s_sum[w][lane]));
            const float z  = 1.f / (1.f + __expf(-s_sum[w][40 + lane]));
            // n = tanh(sx_n + r*sh_n) = tanh(ssum_n + (r-1)*sh_n)
            const float pre = s_sum[w][80 + lane] + (r - 1.f) * s_shn[w][lane];
            const float ex  = __expf(-2.f * pre);
            const float n   = (1.f - ex) / (1.f + ex);
            const float hprev = s_h[w][lane];
            const float hnew  = (1.f - z) * n + z * hprev;
            s_h[w][lane] = hnew;
            if constexpr (WRITE_ALL) {
                out[((size_t)e * T_STEPS + t) * HID + lane] = hnew;
            } else {
                if (t == T_STEPS - 1) out[(size_t)e * HID + lane] = hnew;
            }
        }
        // next iteration's SYNC_A orders the s_h update vs next dots
    }
}

// lay8: a = leaky(h @ w1^T + b1); t = a . w_last + b_last; out = sigmoid(t)
__global__ __launch_bounds__(256) void final_head(
    const float* __restrict__ hlast,  // [CB, 40]
    float* __restrict__ outp,         // [CB]
    const float* __restrict__ w1, const float* __restrict__ b1,
    const float* __restrict__ wl, const float* __restrict__ bl, int n)
{
    __shared__ float s_w1[HID][HID + 1];
    __shared__ float s_b1[HID];
    __shared__ float s_wl[HID];
    for (int i = threadIdx.x; i < HID * HID; i += 256) s_w1[i / HID][i % HID] = w1[i];
    if (threadIdx.x < HID) { s_b1[threadIdx.x] = b1[threadIdx.x]; s_wl[threadIdx.x] = wl[threadIdx.x]; }
    __syncthreads();
    const int e = blockIdx.x * 256 + threadIdx.x;
    if (e >= n) return;
    float h[HID];
    const float4* hv = reinterpret_cast<const float4*>(hlast + (size_t)e * HID);
    #pragma unroll
    for (int k = 0; k < HID / 4; ++k) reinterpret_cast<float4*>(h)[k] = hv[k];
    float acc = bl[0];
    #pragma unroll
    for (int u = 0; u < HID; ++u) {
        float a = s_b1[u];
        #pragma unroll
        for (int d = 0; d < HID; ++d) a += s_w1[u][d] * h[d];
        a = a > 0.f ? a : 0.01f * a;
        acc += a * s_wl[u];
    }
    outp[e] = 1.f / (1.f + __expf(-acc));
}

extern "C" void kernel_launch(void* const* d_in, const int* in_sizes, int n_in,
                              void* d_out, int out_size, void* d_ws, size_t ws_size,
                              hipStream_t stream)
{
    const float* x      = (const float*)d_in[0];
    const float* g0_wih = (const float*)d_in[1];
    const float* g0_whh = (const float*)d_in[2];
    const float* g0_bih = (const float*)d_in[3];
    const float* g0_bhh = (const float*)d_in[4];
    const float* g_wih  = (const float*)d_in[5];   // [4,120,40]
    const float* g_whh  = (const float*)d_in[6];   // [4,120,40]
    const float* g_bih  = (const float*)d_in[7];   // [4,120]
    const float* g_bhh  = (const float*)d_in[8];   // [4,120]
    const float* mlp_w1 = (const float*)d_in[9];   // [4,40,40]
    const float* mlp_b1 = (const float*)d_in[10];  // [4,40]
    const float* mlp_w2 = (const float*)d_in[11];  // [3,40,40]
    const float* mlp_b2 = (const float*)d_in[12];  // [3,40]
    const float* w_last = (const float*)d_in[13];  // [1,40]
    const float* b_last = (const float*)d_in[14];  // [1]

    const int B = in_sizes[0] / (T_STEPS * 20);
    float* out = (float*)d_out;

    // chunk the batch so two [CB,T,40] fp32 ping-pong buffers fit in d_ws
    int CB = B;
    while ((size_t)2 * CB * T_STEPS * HID * sizeof(float) > ws_size && CB > 64) CB >>= 1;
    float* bufA = (float*)d_ws;
    float* bufB = bufA + (size_t)CB * T_STEPS * HID;

    for (int c = 0; c < B; c += CB) {
        const float* xc = x + (size_t)c * T_STEPS * 20;
        const dim3 blk(256), grd(CB / 4);

        // lay1: 2-layer GRU
        gru_fused<20, false, true><<<grd, blk, 0, stream>>>(
            xc, bufA, g0_wih, g0_whh, g0_bih, g0_bhh,
            nullptr, nullptr, nullptr, nullptr);
        gru_fused<40, false, true><<<grd, blk, 0, stream>>>(
            bufA, bufB, g_wih + 0 * 4800, g_whh + 0 * 4800, g_bih + 0 * 120, g_bhh + 0 * 120,
            nullptr, nullptr, nullptr, nullptr);
        // lay2+lay3: MLP0 fused into GRU(g[1])
        gru_fused<40, true, true><<<grd, blk, 0, stream>>>(
            bufB, bufA, g_wih + 1 * 4800, g_whh + 1 * 4800, g_bih + 1 * 120, g_bhh + 1 * 120,
            mlp_w1 + 0 * 1600, mlp_b1 + 0 * 40, mlp_w2 + 0 * 1600, mlp_b2 + 0 * 40);
        // lay4+lay5: MLP1 fused into GRU(g[2])
        gru_fused<40, true, true><<<grd, blk, 0, stream>>>(
            bufA, bufB, g_wih + 2 * 4800, g_whh + 2 * 4800, g_bih + 2 * 120, g_bhh + 2 * 120,
            mlp_w1 + 1 * 1600, mlp_b1 + 1 * 40, mlp_w2 + 1 * 1600, mlp_b2 + 1 * 40);
        // lay6+lay7: MLP2 fused into GRU(g[3]); only last-timestep h needed
        gru_fused<40, true, false><<<grd, blk, 0, stream>>>(
            bufB, bufA, g_wih + 3 * 4800, g_whh + 3 * 4800, g_bih + 3 * 120, g_bhh + 3 * 120,
            mlp_w1 + 2 * 1600, mlp_b1 + 2 * 40, mlp_w2 + 2 * 1600, mlp_b2 + 2 * 40);
        // lay8 head on h[:, -1]
        final_head<<<dim3((CB + 255) / 256), blk, 0, stream>>>(
            bufA, out + c, mlp_w1 + 3 * 1600, mlp_b1 + 3 * 40, w_last, b_last, CB);
    }
}